// Round 8
// baseline (113.690 us; speedup 1.0000x reference)
//
#include <hip/hip_runtime.h>
#include <hip/hip_bf16.h>

// Self_Attn_3D: B=8, H=W=64 (N=4096 tokens), C_IN=256, C_QK=32.
// out[b,n] = gamma * sum_m softmax(q_n.k_m) * vbar[b,m] + xbar[b,n]
//   vbar = x @ mean_j(Wv) + mean(bv);  xbar = mean_c(x)
// (channel-mean commutes through attention output -> scalar-V flash attention)
//
// R10: R7 = 112.6us (best). Flash near floor (~17 vs ~10). Biggest modeled
// slack: proj ~13us vs 5.3us HBM floor, grid-limited at 2 waves/SIMD + a
// 64-thread serial vbar/xbar tail. proj v2: 32-token tiles, grid 1024
// (4 blocks/CU x 4 waves = 4 waves/SIMD, launch_bounds(256,4); LDS 16.9KB);
// MFMA split: wave w -> token-group w&1, output-pair (w>>1)*2..+1.
// vbar/xbar: 8 threads/token, shfl_xor(1,2,4) reduce. prep/flash untouched.

typedef _Float16 half8  __attribute__((ext_vector_type(8)));
typedef _Float16 half4v __attribute__((ext_vector_type(4)));
typedef float    f32x4  __attribute__((ext_vector_type(4)));

#define LOG2E 1.4426950408889634f

#if __has_builtin(__builtin_amdgcn_exp2f)
#define EXP2(x) __builtin_amdgcn_exp2f(x)
#else
#define EXP2(x) exp2f(x)
#endif

// ---------------------------------------------------------------------------
// prep: build (a) Wfr = [Wq|Wk] as f16 in MFMA-B-fragment order
//             Wfr[((ch*4+quad)*64 + col)*8 + j] = W[c=ch*32+quad*8+j][col]
//       (b) wvbar[256] = row-mean of Wv, (c) bvbar = mean(bv)
// grid 129 x 256
// ---------------------------------------------------------------------------
__global__ __launch_bounds__(256) void prep_kernel(
    const float* __restrict__ Wq, const float* __restrict__ Wk,
    const float* __restrict__ Wv, const float* __restrict__ bv,
    _Float16* __restrict__ Wfr, float* __restrict__ wvbar, float* __restrict__ bvbar)
{
  int bid = blockIdx.x, tid = threadIdx.x;
  if (bid < 64) {
    int col = bid, c = tid;
    float v = (col < 32) ? Wq[c * 32 + col] : Wk[c * 32 + (col - 32)];
    int ch = c >> 5, quad = (c >> 3) & 3, j = c & 7;
    Wfr[(size_t)((ch * 4 + quad) * 64 + col) * 8 + j] = (_Float16)v;
  } else if (bid < 128) {
    // one wave per Wv row: row-mean over 256 cols
    int row = (bid - 64) * 4 + (tid >> 6);
    int lane = tid & 63;
    const float* p = Wv + (size_t)row * 256 + lane * 4;
    float s = p[0] + p[1] + p[2] + p[3];
    #pragma unroll
    for (int off = 32; off >= 1; off >>= 1) s += __shfl_xor(s, off);
    if (lane == 0) wvbar[row] = s * (1.0f / 256.0f);
  } else {
    if (tid < 64) {
      const float* p = bv + tid * 4;
      float s = p[0] + p[1] + p[2] + p[3];
      #pragma unroll
      for (int off = 32; off >= 1; off >>= 1) s += __shfl_xor(s, off);
      if (tid == 0) bvbar[0] = s * (1.0f / 256.0f);
    }
  }
}

// ---------------------------------------------------------------------------
// proj v2: per 32-token tile: Qh=(x@Wq+bq)*log2e (f16), Kh=x@Wk+bk (f16),
//          vbar, xbar (f32). MFMA f16 16x16x32, A from LDS, B direct from Wfr.
// grid 1024 x 256, 4 blocks/CU (4 waves/SIMD)
// ---------------------------------------------------------------------------
__global__ __launch_bounds__(256, 4) void proj_kernel(
    const float* __restrict__ x, const _Float16* __restrict__ Wfr,
    const float* __restrict__ bq, const float* __restrict__ bk,
    const float* __restrict__ wvbar, const float* __restrict__ bvbar,
    _Float16* __restrict__ Qh, _Float16* __restrict__ Kh,
    float* __restrict__ vbarO, float* __restrict__ xbarO)
{
  __shared__ _Float16 XT[32 * 264];   // 32 tokens x 256 f16, stride 264 (bank spread)
  int tid = threadIdx.x, blk = blockIdx.x;
  size_t tok0 = (size_t)blk * 32;

  // stage x -> XT (f32->f16), fully coalesced global reads
  const float4* xg4 = (const float4*)x;
  #pragma unroll
  for (int i = 0; i < 8; ++i) {
    int f = i * 256 + tid;            // 0..2047 float4s in this tile
    int tok = f >> 6, c4 = f & 63;
    float4 v = xg4[(size_t)blk * 2048 + f];
    half4v h;
    h.x = (_Float16)v.x; h.y = (_Float16)v.y; h.z = (_Float16)v.z; h.w = (_Float16)v.w;
    *(half4v*)&XT[tok * 264 + c4 * 4] = h;
  }
  __syncthreads();

  // vbar / xbar: 8 threads per token, 32 channels each, shfl-reduce over the
  // 8-lane group (f16-rounded x is fine: error ~1e-5)
  {
    int tok = tid >> 3, t8 = tid & 7;
    float vs = 0.f, xs = 0.f;
    const float4* wv4 = (const float4*)(wvbar + t8 * 32);
    #pragma unroll
    for (int g = 0; g < 4; ++g) {
      half8 h = *(const half8*)&XT[tok * 264 + t8 * 32 + g * 8];
      float4 wa = wv4[g * 2], wb = wv4[g * 2 + 1];
      float x0 = (float)h[0], x1 = (float)h[1], x2 = (float)h[2], x3 = (float)h[3];
      float x4 = (float)h[4], x5 = (float)h[5], x6 = (float)h[6], x7 = (float)h[7];
      vs += ((x0 * wa.x + x1 * wa.y) + (x2 * wa.z + x3 * wa.w))
          + ((x4 * wb.x + x5 * wb.y) + (x6 * wb.z + x7 * wb.w));
      xs += ((x0 + x1) + (x2 + x3)) + ((x4 + x5) + (x6 + x7));
    }
    #pragma unroll
    for (int off = 1; off < 8; off <<= 1) {
      vs += __shfl_xor(vs, off);
      xs += __shfl_xor(xs, off);
    }
    if (t8 == 0) {
      vbarO[tok0 + tok] = vs + bvbar[0];
      xbarO[tok0 + tok] = xs * (1.0f / 256.0f);
    }
  }

  // MFMA: 32 tokens x 64 outputs, K=256 in 8 chunks of 32.
  // wave w: token-group tg = w&1 (tokens tg*16..+15), out-pair ctb = (w>>1)*2
  int lane = tid & 63, w = tid >> 6;
  int l15 = lane & 15, quad = lane >> 4;
  int tg = w & 1, ctb = (w >> 1) * 2;
  f32x4 acc[2] = {(f32x4){0,0,0,0},(f32x4){0,0,0,0}};
  #pragma unroll
  for (int ch = 0; ch < 8; ++ch) {
    half8 a = *(const half8*)&XT[(tg * 16 + l15) * 264 + ch * 32 + quad * 8];
    #pragma unroll
    for (int cti = 0; cti < 2; ++cti) {
      int ct = ctb + cti;
      half8 bf = *(const half8*)(Wfr + (size_t)((ch * 4 + quad) * 64 + ct * 16 + l15) * 8);
      acc[cti] = __builtin_amdgcn_mfma_f32_16x16x32_f16(a, bf, acc[cti], 0, 0, 0);
    }
  }
  // epilogue: D layout col=lane&15, row=quad*4+reg
  #pragma unroll
  for (int cti = 0; cti < 2; ++cti) {
    int ct = ctb + cti;
    int col = ct * 16 + l15;
    #pragma unroll
    for (int r = 0; r < 4; ++r) {
      int token = tg * 16 + quad * 4 + r;
      if (ct < 2) {
        float val = (acc[cti][r] + bq[col]) * LOG2E;     // fold log2e into Q
        Qh[(tok0 + token) * 32 + col] = (_Float16)val;
      } else {
        float val = acc[cti][r] + bk[col - 32];
        Kh[(tok0 + token) * 32 + (col - 32)] = (_Float16)val;
      }
    }
  }
}

// ---------------------------------------------------------------------------
// flash v5 (R7-proven): scalar-V attention, K-split across 8 waves. One block
// = 64 Q-rows of one batch, 512 threads; wave w owns keys [w*512, (w+1)*512)
// -- each K byte read ONCE per block; 4 waves/SIMD for latency hiding. Each
// wave carries 4 A-fragments covering all 64 Q rows. K B-fragments read
// DIRECTLY from global (layout == MFMA B operand; 1 KB coalesced per load,
// L2-hot). Static-max softmax: s = q.k*log2e - 88 via MFMA C bias; p = 2^s.
// Cross-wave (sum_p, sum_p*v) combine via 4 KB LDS + one barrier.
// grid 512 x 512
// ---------------------------------------------------------------------------
__global__ __launch_bounds__(512, 4) void flash_kernel(
    const _Float16* __restrict__ Qh, const _Float16* __restrict__ Kh,
    const float* __restrict__ vbar, const float* __restrict__ xbar,
    const float* __restrict__ gamma, float* __restrict__ out)
{
  __shared__ float Lp[8][64];
  __shared__ float Op[8][64];
  int tid = threadIdx.x, blk = blockIdx.x;
  int b = blk >> 6, qt = blk & 63;
  int lane = tid & 63, w = tid >> 6;      // w = 0..7
  int l15 = lane & 15, quad = lane >> 4;

  const _Float16* Qb = Qh + (size_t)b * 4096 * 32;
  const _Float16* Kb = Kh + (size_t)b * 4096 * 32;
  const float* vb = vbar + (size_t)b * 4096;

  // 4 Q fragments covering all 64 rows of this tile: A[m=lane&15][k=quad*8+j]
  half8 aq[4];
  #pragma unroll
  for (int af = 0; af < 4; ++af)
    aq[af] = *(const half8*)(Qb + (size_t)(qt * 64 + af * 16 + l15) * 32 + quad * 8);

  float lacc[4][4], oacc[4][4];
  #pragma unroll
  for (int af = 0; af < 4; ++af)
    #pragma unroll
    for (int r = 0; r < 4; ++r) { lacc[af][r] = 0.f; oacc[af][r] = 0.f; }
  const f32x4 cinit = {-88.f, -88.f, -88.f, -88.f};

  // wave w's 512-key slice: B-fragment base for this lane
  const _Float16* kfrag = Kb + ((size_t)w * 512 + l15) * 32 + quad * 8;
  const float* vfrag = vb + w * 512 + l15;

  #pragma unroll 2
  for (int kt = 0; kt < 8; ++kt) {
    half8 bk8[4];
    float vbl[4];
    #pragma unroll
    for (int ct = 0; ct < 4; ++ct) {
      bk8[ct] = *(const half8*)(kfrag + (size_t)(kt * 64 + ct * 16) * 32);
      vbl[ct] = vfrag[kt * 64 + ct * 16];
    }
    #pragma unroll
    for (int af = 0; af < 4; ++af) {
      f32x4 sc[4];
      #pragma unroll
      for (int ct = 0; ct < 4; ++ct)
        sc[ct] = __builtin_amdgcn_mfma_f32_16x16x32_f16(aq[af], bk8[ct], cinit, 0, 0, 0);
      #pragma unroll
      for (int r = 0; r < 4; ++r) {   // rows quad*4+r; cols ct*16+(lane&15)
        float p0 = EXP2(sc[0][r]), p1 = EXP2(sc[1][r]);
        float p2 = EXP2(sc[2][r]), p3 = EXP2(sc[3][r]);
        lacc[af][r] += (p0 + p1) + (p2 + p3);
        oacc[af][r] += ((p0 * vbl[0] + p1 * vbl[1]) + (p2 * vbl[2] + p3 * vbl[3]));
      }
    }
  }

  // reduce partials across the 16 lanes sharing a quad
  #pragma unroll
  for (int af = 0; af < 4; ++af)
    #pragma unroll
    for (int r = 0; r < 4; ++r) {
      #pragma unroll
      for (int off = 1; off < 16; off <<= 1) {
        lacc[af][r] += __shfl_xor(lacc[af][r], off);
        oacc[af][r] += __shfl_xor(oacc[af][r], off);
      }
    }

  // cross-wave combine: wave w's partial for row af*16+quad*4+r
  if (l15 == 0) {
    #pragma unroll
    for (int af = 0; af < 4; ++af)
      #pragma unroll
      for (int r = 0; r < 4; ++r) {
        Lp[w][af * 16 + quad * 4 + r] = lacc[af][r];
        Op[w][af * 16 + quad * 4 + r] = oacc[af][r];
      }
  }
  __syncthreads();
  if (tid < 64) {
    float l = ((Lp[0][tid] + Lp[1][tid]) + (Lp[2][tid] + Lp[3][tid]))
            + ((Lp[4][tid] + Lp[5][tid]) + (Lp[6][tid] + Lp[7][tid]));
    float o = ((Op[0][tid] + Op[1][tid]) + (Op[2][tid] + Op[3][tid]))
            + ((Op[4][tid] + Op[5][tid]) + (Op[6][tid] + Op[7][tid]));
    size_t g = (size_t)b * 4096 + qt * 64 + tid;
    out[g] = gamma[0] * (o / l) + xbar[g];
  }
}

// ---------------------------------------------------------------------------
extern "C" void kernel_launch(void* const* d_in, const int* in_sizes, int n_in,
                              void* d_out, int out_size, void* d_ws, size_t ws_size,
                              hipStream_t stream)
{
  const float* x     = (const float*)d_in[0];
  const float* Wq    = (const float*)d_in[1];
  const float* bq    = (const float*)d_in[2];
  const float* Wk    = (const float*)d_in[3];
  const float* bk    = (const float*)d_in[4];
  const float* Wv    = (const float*)d_in[5];
  const float* bv    = (const float*)d_in[6];
  const float* gamma = (const float*)d_in[7];
  float* out = (float*)d_out;

  char* ws = (char*)d_ws;                          // needs ~4.6 MB
  _Float16* Wfr  = (_Float16*)(ws);                // 32 KB
  float* wvbar   = (float*)(ws + 32768);           // 1 KB
  float* bvbar   = (float*)(ws + 33792);           // 4 B
  _Float16* Qh   = (_Float16*)(ws + 65536);        // 2 MB
  _Float16* Kh   = (_Float16*)(ws + 65536 + 2097152);        // 2 MB
  float* vbarA   = (float*)(ws + 65536 + 4194304);           // 128 KB
  float* xbarA   = (float*)(ws + 65536 + 4194304 + 131072);  // 128 KB

  prep_kernel<<<129, 256, 0, stream>>>(Wq, Wk, Wv, bv, Wfr, wvbar, bvbar);
  proj_kernel<<<1024, 256, 0, stream>>>(x, Wfr, bq, bk, wvbar, bvbar, Qh, Kh, vbarA, xbarA);
  flash_kernel<<<512, 512, 0, stream>>>(Qh, Kh, vbarA, xbarA, gamma, out);
}

// Round 9
// 112.487 us; speedup vs baseline: 1.0107x; 1.0107x over previous
//
#include <hip/hip_runtime.h>
#include <hip/hip_bf16.h>

// Self_Attn_3D: B=8, H=W=64 (N=4096 tokens), C_IN=256, C_QK=32.
// out[b,n] = gamma * sum_m softmax(q_n.k_m) * vbar[b,m] + xbar[b,n]
//   vbar = x @ mean_j(Wv) + mean(bv);  xbar = mean_c(x)
// (channel-mean commutes through attention output -> scalar-V flash attention)
//
// R11: REVERT to the R7-proven best (112.6us). R8's proj occupancy-split
// (grid 1024, 32-token tiles) was neutral (+1.1us): proj is HBM-stream +
// write-back bound, not occupancy-bound -- doubling blocks doubled fixed
// cost. Ledger of levers: prep-merge LOSES (128MB redundant Wv L2 reads),
// grid-sync fusion LOSES (barrier ~140us), flash K-split/8-wave WINS
// (R6+R7: -13.2us, now saturated at 4 waves/SIMD), proj occupancy NEUTRAL.
// Structural floor ~= 69us fixed harness + 5.6us proj HBM + ~10us flash
// trans/VALU + prep/gaps.

typedef _Float16 half8  __attribute__((ext_vector_type(8)));
typedef _Float16 half4v __attribute__((ext_vector_type(4)));
typedef float    f32x4  __attribute__((ext_vector_type(4)));

#define LOG2E 1.4426950408889634f

#if __has_builtin(__builtin_amdgcn_exp2f)
#define EXP2(x) __builtin_amdgcn_exp2f(x)
#else
#define EXP2(x) exp2f(x)
#endif

// ---------------------------------------------------------------------------
// prep: build (a) Wfr = [Wq|Wk] as f16 in MFMA-B-fragment order
//             Wfr[((ch*4+quad)*64 + col)*8 + j] = W[c=ch*32+quad*8+j][col]
//       (b) wvbar[256] = row-mean of Wv, (c) bvbar = mean(bv)
// grid 129 x 256
// ---------------------------------------------------------------------------
__global__ __launch_bounds__(256) void prep_kernel(
    const float* __restrict__ Wq, const float* __restrict__ Wk,
    const float* __restrict__ Wv, const float* __restrict__ bv,
    _Float16* __restrict__ Wfr, float* __restrict__ wvbar, float* __restrict__ bvbar)
{
  int bid = blockIdx.x, tid = threadIdx.x;
  if (bid < 64) {
    int col = bid, c = tid;
    float v = (col < 32) ? Wq[c * 32 + col] : Wk[c * 32 + (col - 32)];
    int ch = c >> 5, quad = (c >> 3) & 3, j = c & 7;
    Wfr[(size_t)((ch * 4 + quad) * 64 + col) * 8 + j] = (_Float16)v;
  } else if (bid < 128) {
    // one wave per Wv row: row-mean over 256 cols
    int row = (bid - 64) * 4 + (tid >> 6);
    int lane = tid & 63;
    const float* p = Wv + (size_t)row * 256 + lane * 4;
    float s = p[0] + p[1] + p[2] + p[3];
    #pragma unroll
    for (int off = 32; off >= 1; off >>= 1) s += __shfl_xor(s, off);
    if (lane == 0) wvbar[row] = s * (1.0f / 256.0f);
  } else {
    if (tid < 64) {
      const float* p = bv + tid * 4;
      float s = p[0] + p[1] + p[2] + p[3];
      #pragma unroll
      for (int off = 32; off >= 1; off >>= 1) s += __shfl_xor(s, off);
      if (tid == 0) bvbar[0] = s * (1.0f / 256.0f);
    }
  }
}

// ---------------------------------------------------------------------------
// proj (R7-proven): per 64-token tile: Qh=(x@Wq+bq)*log2e (f16),
//       Kh=x@Wk+bk (f16), vbar, xbar (f32). MFMA f16 16x16x32, A from LDS,
//       B direct from Wfr. grid 512 x 256
// ---------------------------------------------------------------------------
__global__ __launch_bounds__(256) void proj_kernel(
    const float* __restrict__ x, const _Float16* __restrict__ Wfr,
    const float* __restrict__ bq, const float* __restrict__ bk,
    const float* __restrict__ wvbar, const float* __restrict__ bvbar,
    _Float16* __restrict__ Qh, _Float16* __restrict__ Kh,
    float* __restrict__ vbarO, float* __restrict__ xbarO)
{
  __shared__ _Float16 XT[64 * 264];   // 64 tokens x 256 f16, stride 264 (bank spread)
  int tid = threadIdx.x, blk = blockIdx.x;
  size_t tok0 = (size_t)blk * 64;

  // stage x -> XT (f32->f16), fully coalesced global reads
  const float4* xg4 = (const float4*)x;
  #pragma unroll
  for (int i = 0; i < 16; ++i) {
    int f = i * 256 + tid;            // 0..4095 float4s in this tile
    int tok = f >> 6, c4 = f & 63;
    float4 v = xg4[(size_t)blk * 4096 + f];
    half4v h;
    h.x = (_Float16)v.x; h.y = (_Float16)v.y; h.z = (_Float16)v.z; h.w = (_Float16)v.w;
    *(half4v*)&XT[tok * 264 + c4 * 4] = h;
  }
  __syncthreads();

  // vbar / xbar: one thread per token (f16-rounded x is fine: error ~1e-5)
  if (tid < 64) {
    float vs = 0.f, xs = 0.f;
    #pragma unroll 4
    for (int g = 0; g < 32; ++g) {
      half8 h = *(const half8*)&XT[tid * 264 + g * 8];
      #pragma unroll
      for (int j = 0; j < 8; ++j) {
        float xv = (float)h[j];
        vs += xv * wvbar[g * 8 + j];   // uniform -> s_load
        xs += xv;
      }
    }
    vbarO[tok0 + tid] = vs + bvbar[0];
    xbarO[tok0 + tid] = xs * (1.0f / 256.0f);
  }

  // MFMA: 64 tokens x 64 outputs, K=256 in 8 chunks of 32
  int lane = tid & 63, w = tid >> 6;
  int l15 = lane & 15, quad = lane >> 4;
  f32x4 acc[4] = {(f32x4){0,0,0,0},(f32x4){0,0,0,0},(f32x4){0,0,0,0},(f32x4){0,0,0,0}};
  #pragma unroll
  for (int ch = 0; ch < 8; ++ch) {
    half8 a = *(const half8*)&XT[(w * 16 + l15) * 264 + ch * 32 + quad * 8];
    #pragma unroll
    for (int ct = 0; ct < 4; ++ct) {
      half8 bf = *(const half8*)(Wfr + (size_t)((ch * 4 + quad) * 64 + ct * 16 + l15) * 8);
      acc[ct] = __builtin_amdgcn_mfma_f32_16x16x32_f16(a, bf, acc[ct], 0, 0, 0);
    }
  }
  // epilogue: D layout col=lane&15, row=quad*4+reg
  #pragma unroll
  for (int ct = 0; ct < 4; ++ct) {
    int col = ct * 16 + l15;
    #pragma unroll
    for (int r = 0; r < 4; ++r) {
      int token = w * 16 + quad * 4 + r;
      if (ct < 2) {
        float val = (acc[ct][r] + bq[col]) * LOG2E;      // fold log2e into Q
        Qh[(tok0 + token) * 32 + col] = (_Float16)val;
      } else {
        float val = acc[ct][r] + bk[col - 32];
        Kh[(tok0 + token) * 32 + (col - 32)] = (_Float16)val;
      }
    }
  }
}

// ---------------------------------------------------------------------------
// flash v5 (R7-proven): scalar-V attention, K-split across 8 waves. One block
// = 64 Q-rows of one batch, 512 threads; wave w owns keys [w*512, (w+1)*512)
// -- each K byte read ONCE per block; 4 waves/SIMD for latency hiding. Each
// wave carries 4 A-fragments covering all 64 Q rows. K B-fragments read
// DIRECTLY from global (layout == MFMA B operand; 1 KB coalesced per load,
// L2-hot). Static-max softmax: s = q.k*log2e - 88 via MFMA C bias; p = 2^s.
// Cross-wave (sum_p, sum_p*v) combine via 4 KB LDS + one barrier.
// grid 512 x 512
// ---------------------------------------------------------------------------
__global__ __launch_bounds__(512, 4) void flash_kernel(
    const _Float16* __restrict__ Qh, const _Float16* __restrict__ Kh,
    const float* __restrict__ vbar, const float* __restrict__ xbar,
    const float* __restrict__ gamma, float* __restrict__ out)
{
  __shared__ float Lp[8][64];
  __shared__ float Op[8][64];
  int tid = threadIdx.x, blk = blockIdx.x;
  int b = blk >> 6, qt = blk & 63;
  int lane = tid & 63, w = tid >> 6;      // w = 0..7
  int l15 = lane & 15, quad = lane >> 4;

  const _Float16* Qb = Qh + (size_t)b * 4096 * 32;
  const _Float16* Kb = Kh + (size_t)b * 4096 * 32;
  const float* vb = vbar + (size_t)b * 4096;

  // 4 Q fragments covering all 64 rows of this tile: A[m=lane&15][k=quad*8+j]
  half8 aq[4];
  #pragma unroll
  for (int af = 0; af < 4; ++af)
    aq[af] = *(const half8*)(Qb + (size_t)(qt * 64 + af * 16 + l15) * 32 + quad * 8);

  float lacc[4][4], oacc[4][4];
  #pragma unroll
  for (int af = 0; af < 4; ++af)
    #pragma unroll
    for (int r = 0; r < 4; ++r) { lacc[af][r] = 0.f; oacc[af][r] = 0.f; }
  const f32x4 cinit = {-88.f, -88.f, -88.f, -88.f};

  // wave w's 512-key slice: B-fragment base for this lane
  const _Float16* kfrag = Kb + ((size_t)w * 512 + l15) * 32 + quad * 8;
  const float* vfrag = vb + w * 512 + l15;

  #pragma unroll 2
  for (int kt = 0; kt < 8; ++kt) {
    half8 bk8[4];
    float vbl[4];
    #pragma unroll
    for (int ct = 0; ct < 4; ++ct) {
      bk8[ct] = *(const half8*)(kfrag + (size_t)(kt * 64 + ct * 16) * 32);
      vbl[ct] = vfrag[kt * 64 + ct * 16];
    }
    #pragma unroll
    for (int af = 0; af < 4; ++af) {
      f32x4 sc[4];
      #pragma unroll
      for (int ct = 0; ct < 4; ++ct)
        sc[ct] = __builtin_amdgcn_mfma_f32_16x16x32_f16(aq[af], bk8[ct], cinit, 0, 0, 0);
      #pragma unroll
      for (int r = 0; r < 4; ++r) {   // rows quad*4+r; cols ct*16+(lane&15)
        float p0 = EXP2(sc[0][r]), p1 = EXP2(sc[1][r]);
        float p2 = EXP2(sc[2][r]), p3 = EXP2(sc[3][r]);
        lacc[af][r] += (p0 + p1) + (p2 + p3);
        oacc[af][r] += ((p0 * vbl[0] + p1 * vbl[1]) + (p2 * vbl[2] + p3 * vbl[3]));
      }
    }
  }

  // reduce partials across the 16 lanes sharing a quad
  #pragma unroll
  for (int af = 0; af < 4; ++af)
    #pragma unroll
    for (int r = 0; r < 4; ++r) {
      #pragma unroll
      for (int off = 1; off < 16; off <<= 1) {
        lacc[af][r] += __shfl_xor(lacc[af][r], off);
        oacc[af][r] += __shfl_xor(oacc[af][r], off);
      }
    }

  // cross-wave combine: wave w's partial for row af*16+quad*4+r
  if (l15 == 0) {
    #pragma unroll
    for (int af = 0; af < 4; ++af)
      #pragma unroll
      for (int r = 0; r < 4; ++r) {
        Lp[w][af * 16 + quad * 4 + r] = lacc[af][r];
        Op[w][af * 16 + quad * 4 + r] = oacc[af][r];
      }
  }
  __syncthreads();
  if (tid < 64) {
    float l = ((Lp[0][tid] + Lp[1][tid]) + (Lp[2][tid] + Lp[3][tid]))
            + ((Lp[4][tid] + Lp[5][tid]) + (Lp[6][tid] + Lp[7][tid]));
    float o = ((Op[0][tid] + Op[1][tid]) + (Op[2][tid] + Op[3][tid]))
            + ((Op[4][tid] + Op[5][tid]) + (Op[6][tid] + Op[7][tid]));
    size_t g = (size_t)b * 4096 + qt * 64 + tid;
    out[g] = gamma[0] * (o / l) + xbar[g];
  }
}

// ---------------------------------------------------------------------------
extern "C" void kernel_launch(void* const* d_in, const int* in_sizes, int n_in,
                              void* d_out, int out_size, void* d_ws, size_t ws_size,
                              hipStream_t stream)
{
  const float* x     = (const float*)d_in[0];
  const float* Wq    = (const float*)d_in[1];
  const float* bq    = (const float*)d_in[2];
  const float* Wk    = (const float*)d_in[3];
  const float* bk    = (const float*)d_in[4];
  const float* Wv    = (const float*)d_in[5];
  const float* bv    = (const float*)d_in[6];
  const float* gamma = (const float*)d_in[7];
  float* out = (float*)d_out;

  char* ws = (char*)d_ws;                          // needs ~4.6 MB
  _Float16* Wfr  = (_Float16*)(ws);                // 32 KB
  float* wvbar   = (float*)(ws + 32768);           // 1 KB
  float* bvbar   = (float*)(ws + 33792);           // 4 B
  _Float16* Qh   = (_Float16*)(ws + 65536);        // 2 MB
  _Float16* Kh   = (_Float16*)(ws + 65536 + 2097152);        // 2 MB
  float* vbarA   = (float*)(ws + 65536 + 4194304);           // 128 KB
  float* xbarA   = (float*)(ws + 65536 + 4194304 + 131072);  // 128 KB

  prep_kernel<<<129, 256, 0, stream>>>(Wq, Wk, Wv, bv, Wfr, wvbar, bvbar);
  proj_kernel<<<512, 256, 0, stream>>>(x, Wfr, bq, bk, wvbar, bvbar, Qh, Kh, vbarA, xbarA);
  flash_kernel<<<512, 512, 0, stream>>>(Qh, Kh, vbarA, xbarA, gamma, out);
}